// Round 17
// baseline (132.543 us; speedup 1.0000x reference)
//
#include <hip/hip_runtime.h>

// ---------------------------------------------------------------------------
// TreeConv GNN. R16: CSR-build trims.
//   - bucket_hist merged into prep via RACE-FREE partial histograms:
//     128 hist blocks write private LDS hists to hist_part[bucket][blk]
//     (plain stores, no zeroed global needed); scan sums the partials.
//     Hist now runs concurrent with x->bf16 conversion; one launch fewer.
//   - partition CHUNK 8192->4096 (LDS 56->32KB, 196->391 blocks).
//   fused0/fused1 unchanged from R15 (62% occ gather + all-wave GEMM).
// ---------------------------------------------------------------------------

#define NPB 256       // nodes per bucket (fill); bucket id = dst >> 8
#define NBMAX 512     // max buckets (n <= 131072)
#define CHUNK 4096    // edges per partition block
#define NH 128        // hist partial blocks

typedef __attribute__((ext_vector_type(8))) short short8;
typedef __attribute__((ext_vector_type(4))) float f32x4;

__device__ inline unsigned int bfbits(float f) {  // RNE f32 -> bf16 bits
  unsigned int x = __float_as_uint(f);
  return (x + 0x7fffu + ((x >> 16) & 1u)) >> 16;
}
__device__ inline unsigned int packbf(float a, float b) {
  return bfbits(a) | (bfbits(b) << 16);
}
__device__ inline float bflo(unsigned int u) {
  return __uint_as_float(u << 16);
}
__device__ inline float bfhi(unsigned int u) {
  return __uint_as_float(u & 0xffff0000u);
}

// ---------------------------------------------------------------------------
// prep: blocks [0,NH) -> partial bucket histograms (race-free);
//       block NH -> weight fragment repack; blocks NH+1.. -> x to bf16.
// wfrag: [0,4)=W1_0 [4,12)=W2_0 [12,20)=W1_1 [20,28)=W2_1 [28,36)=CW1
// [36,38)=CW2(N=16).
// ---------------------------------------------------------------------------
__global__ __launch_bounds__(256) void prep_kernel(
    const float4* __restrict__ x, uint2* __restrict__ xbf, int n4,
    const int* __restrict__ dst, int ne, int nb,
    int* __restrict__ hist_part,
    const float* __restrict__ w1_0, const float* __restrict__ w2_0,
    const float* __restrict__ w1_1, const float* __restrict__ w2_1,
    const float* __restrict__ cw1, const float* __restrict__ cw2,
    uint4* __restrict__ wfrag) {
  const int bid = blockIdx.x;
  if (bid < NH) {  // partial histogram over this block's edge range
    __shared__ int h[NBMAX];
    for (int i = threadIdx.x; i < nb; i += 256) h[i] = 0;
    __syncthreads();
    const int eb = (ne + NH - 1) / NH;
    const int e0 = bid * eb;
    const int e1 = min(e0 + eb, ne);
    for (int e = e0 + threadIdx.x; e < e1; e += 256)
      atomicAdd(&h[dst[e] >> 8], 1);
    __syncthreads();
    for (int i = threadIdx.x; i < nb; i += 256)
      hist_part[i * NH + bid] = h[i];  // plain store, no pre-zero needed
    return;
  }
  if (bid == NH) {  // weight repack
    for (int idx = threadIdx.x; idx < 38 * 64; idx += 256) {
      const int f = idx >> 6, l = idx & 63;
      const float* W;
      int N = 64, f0;
      if (f < 4) { W = w1_0; f0 = f; }
      else if (f < 12) { W = w2_0; f0 = f - 4; }
      else if (f < 20) { W = w1_1; f0 = f - 12; }
      else if (f < 28) { W = w2_1; f0 = f - 20; }
      else if (f < 36) { W = cw1; f0 = f - 28; }
      else { W = cw2; f0 = f - 36; N = 16; }
      int kb, t;
      if (N == 16) { kb = f0; t = 0; } else { kb = f0 >> 2; t = f0 & 3; }
      const int k0 = kb * 32 + (l >> 4) * 8;
      const int col = t * 16 + (l & 15);
      unsigned int p[4];
#pragma unroll
      for (int j = 0; j < 4; j++)
        p[j] =
            packbf(W[(k0 + 2 * j) * N + col], W[(k0 + 2 * j + 1) * N + col]);
      wfrag[idx] = make_uint4(p[0], p[1], p[2], p[3]);
    }
    return;
  }
  const int i = (bid - NH - 1) * 256 + threadIdx.x;
  if (i < n4) {
    const float4 v = x[i];
    xbf[i] = make_uint2(packbf(v.x, v.y), packbf(v.z, v.w));
  }
}

// One block: sum partials per bucket, exclusive scan -> boff, init bcur.
__global__ __launch_bounds__(512) void bucket_scan_kernel(
    const int* __restrict__ hist_part, int* __restrict__ boff,
    int* __restrict__ bcur, int nb, int ne) {
  __shared__ int wsum[8];
  const int lane = threadIdx.x & 63;
  const int wid = threadIdx.x >> 6;
  int v = 0;
  if (threadIdx.x < nb) {
    const int4* p = (const int4*)&hist_part[threadIdx.x * NH];
#pragma unroll
    for (int j = 0; j < NH / 4; j++) {
      const int4 q = p[j];
      v += q.x + q.y + q.z + q.w;
    }
  }
  int x = v;
#pragma unroll
  for (int s = 1; s < 64; s <<= 1) {
    int t = __shfl_up(x, s, 64);
    if (lane >= s) x += t;
  }
  if (lane == 63) wsum[wid] = x;
  __syncthreads();
  if (wid == 0 && lane < 8) {
    int y = wsum[lane];
#pragma unroll
    for (int s = 1; s < 8; s <<= 1) {
      int t = __shfl_up(y, s, 64);
      if (lane >= s) y += t;
    }
    wsum[lane] = y;
  }
  __syncthreads();
  const int wbase = (wid == 0) ? 0 : wsum[wid - 1];
  const int excl = wbase + x - v;
  if (threadIdx.x < nb) {
    boff[threadIdx.x] = excl;
    bcur[threadIdx.x] = excl;
  }
  if (threadIdx.x == 0) boff[nb] = ne;
}

__global__ __launch_bounds__(256) void partition_kernel(
    const int* __restrict__ src, const int* __restrict__ dst,
    int* __restrict__ bcur, int* __restrict__ sorted, int ne, int nb) {
  __shared__ int hist[NBMAX];
  __shared__ int lbase[NBMAX];
  __shared__ int gbase[NBMAX];
  __shared__ int cur[NBMAX];
  __shared__ int vals[CHUNK];
  __shared__ unsigned short bins[CHUNK];

  const int tid = threadIdx.x;
  const int e0 = blockIdx.x * CHUNK;
  const int m = min(CHUNK, ne - e0);

  for (int i = tid; i < nb; i += 256) hist[i] = 0;
  __syncthreads();
  for (int i = tid; i < m; i += 256) atomicAdd(&hist[dst[e0 + i] >> 8], 1);
  __syncthreads();

  if (tid < 64) {
    int v8[8];
    int tot = 0;
#pragma unroll
    for (int k = 0; k < 8; k++) {
      const int b = tid * 8 + k;
      v8[k] = (b < nb) ? hist[b] : 0;
      tot += v8[k];
    }
    int x = tot;
#pragma unroll
    for (int s = 1; s < 64; s <<= 1) {
      int t = __shfl_up(x, s, 64);
      if ((tid & 63) >= s) x += t;
    }
    int run = x - tot;
#pragma unroll
    for (int k = 0; k < 8; k++) {
      const int b = tid * 8 + k;
      if (b < nb) {
        lbase[b] = run;
        run += v8[k];
      }
    }
  }
  __syncthreads();

  for (int b = tid; b < nb; b += 256) {
    const int c = hist[b];
    cur[b] = lbase[b];
    gbase[b] = c ? atomicAdd(&bcur[b], c) : 0;
  }
  __syncthreads();

  for (int i = tid; i < m; i += 256) {
    const int s = src[e0 + i];
    const int d = dst[e0 + i];
    const int b = d >> 8;
    const int p = atomicAdd(&cur[b], 1);
    vals[p] = s | ((d & 255) << 17);
    bins[p] = (unsigned short)b;
  }
  __syncthreads();

  for (int i = tid; i < m; i += 256) {
    const int b = bins[i];
    sorted[gbase[b] + (i - lbase[b])] = vals[i];
  }
}

__global__ __launch_bounds__(256) void fill_bucket_kernel(
    const int* __restrict__ sorted, const int* __restrict__ boff,
    int* __restrict__ off, int* __restrict__ csr, int n, int ne) {
  __shared__ int hist[NPB];
  __shared__ int cur[NPB];
  __shared__ int wsum[4];
  const int tid = threadIdx.x;
  const int b = blockIdx.x;
  const int e0 = boff[b];
  const int m = boff[b + 1] - e0;

  hist[tid] = 0;
  __syncthreads();
  for (int i = tid; i < m; i += 256) atomicAdd(&hist[sorted[e0 + i] >> 17], 1);
  __syncthreads();

  const int lane = tid & 63;
  const int wid = tid >> 6;
  const int v = hist[tid];
  int x = v;
#pragma unroll
  for (int s = 1; s < 64; s <<= 1) {
    int t = __shfl_up(x, s, 64);
    if (lane >= s) x += t;
  }
  if (lane == 63) wsum[wid] = x;
  __syncthreads();
  if (tid == 0) {
    int s = 0;
#pragma unroll
    for (int k = 0; k < 4; k++) {
      const int t = wsum[k];
      wsum[k] = s;
      s += t;
    }
  }
  __syncthreads();
  const int excl = wsum[wid] + x - v;
  cur[tid] = excl;
  const int node = b * NPB + tid;
  if (node < n) off[node] = e0 + excl;
  if (b == 0 && tid == 0) off[n] = ne;
  __syncthreads();

  for (int i = tid; i < m; i += 256) {
    const int pv = sorted[e0 + i];
    const int r = atomicAdd(&cur[pv >> 17], 1);
    csr[e0 + r] = pv & 0x1FFFF;
  }
}

// ---------------------------------------------------------------------------
// One wave computes NT 16x16 output tiles at (row16, tbase..tbase+NT-1) of
// D = A(LDS) @ W + bias. Caller places __syncthreads() between stages.
// ---------------------------------------------------------------------------
template <int KB, int NT, bool RELU>
__device__ inline void gemm_tiles(const unsigned short* __restrict__ src,
                                  int srcs, unsigned short* __restrict__ dst,
                                  const short8* __restrict__ wfrag,
                                  const float* __restrict__ bias, int row16,
                                  int tbase, int lane) {
  const int l15 = lane & 15, lh = lane >> 4;
  short8 bf[KB][NT];
#pragma unroll
  for (int kb = 0; kb < KB; kb++)
#pragma unroll
    for (int t = 0; t < NT; t++)
      bf[kb][t] = wfrag[(kb * 4 + tbase + t) * 64 + lane];
  f32x4 acc[NT];
#pragma unroll
  for (int t = 0; t < NT; t++) acc[t] = (f32x4){0.f, 0.f, 0.f, 0.f};
#pragma unroll
  for (int kb = 0; kb < KB; kb++) {
    const short8 a =
        *(const short8*)&src[(row16 * 16 + l15) * srcs + kb * 32 + lh * 8];
#pragma unroll
    for (int t = 0; t < NT; t++)
      acc[t] =
          __builtin_amdgcn_mfma_f32_16x16x32_bf16(a, bf[kb][t], acc[t], 0, 0, 0);
  }
#pragma unroll
  for (int t = 0; t < NT; t++) {
    const float bv = bias[(tbase + t) * 16 + l15];
#pragma unroll
    for (int r = 0; r < 4; r++) {
      float v = acc[t][r] + bv;
      if (RELU) v = fmaxf(v, 0.f);
      dst[(row16 * 16 + lh * 4 + r) * 72 + (tbase + t) * 16 + l15] =
          (unsigned short)bfbits(v);
    }
  }
}

// ---------------------------------------------------------------------------
// fused0: gather(xbf, D=32) -> GEMM(w1_0)+relu -> GEMM(w2_0) -> h0bf.
// 512 thr, 64 nodes/block, 8 thr/node (q4 = sub&3, h = sub>>2), shfl lane^4.
// ---------------------------------------------------------------------------
__global__ __launch_bounds__(512) void fused0_kernel(
    const uint4* __restrict__ xbf, const int* __restrict__ off,
    const int* __restrict__ csr, const short8* __restrict__ wf,
    const float* __restrict__ b1, const float* __restrict__ b2,
    uint4* __restrict__ h0bf, int n) {
  __shared__ unsigned short zsA[64 * 72];
  __shared__ unsigned short zsB[64 * 72];
  const int tid = threadIdx.x;
  const int lane = tid & 63;
  const int wid = tid >> 6;
  const int n0 = blockIdx.x * 64;

  {
    const int node = tid >> 3;
    const int sub = tid & 7;
    const int q4 = sub & 3;
    const int h = sub >> 2;
    const int g = n0 + node;
    float a[8];
#pragma unroll
    for (int i = 0; i < 8; i++) a[i] = 0.f;
    if (g < n) {
      if (h == 0) {
        const uint4 u = xbf[(size_t)g * 4 + q4];
        a[0] = bflo(u.x); a[1] = bfhi(u.x); a[2] = bflo(u.y); a[3] = bfhi(u.y);
        a[4] = bflo(u.z); a[5] = bfhi(u.z); a[6] = bflo(u.w); a[7] = bfhi(u.w);
      }
      const int e0 = off[g], e1 = off[g + 1];
      int e = e0 + h;
      for (; e + 6 < e1; e += 8) {
        const int s0 = csr[e], s1 = csr[e + 2], s2 = csr[e + 4],
                  s3 = csr[e + 6];
        const uint4 u0 = xbf[(size_t)s0 * 4 + q4];
        const uint4 u1 = xbf[(size_t)s1 * 4 + q4];
        const uint4 u2 = xbf[(size_t)s2 * 4 + q4];
        const uint4 u3 = xbf[(size_t)s3 * 4 + q4];
        a[0] += bflo(u0.x) + bflo(u1.x) + bflo(u2.x) + bflo(u3.x);
        a[1] += bfhi(u0.x) + bfhi(u1.x) + bfhi(u2.x) + bfhi(u3.x);
        a[2] += bflo(u0.y) + bflo(u1.y) + bflo(u2.y) + bflo(u3.y);
        a[3] += bfhi(u0.y) + bfhi(u1.y) + bfhi(u2.y) + bfhi(u3.y);
        a[4] += bflo(u0.z) + bflo(u1.z) + bflo(u2.z) + bflo(u3.z);
        a[5] += bfhi(u0.z) + bfhi(u1.z) + bfhi(u2.z) + bfhi(u3.z);
        a[6] += bflo(u0.w) + bflo(u1.w) + bflo(u2.w) + bflo(u3.w);
        a[7] += bfhi(u0.w) + bfhi(u1.w) + bfhi(u2.w) + bfhi(u3.w);
      }
      for (; e < e1; e += 2) {
        const uint4 u4 = xbf[(size_t)csr[e] * 4 + q4];
        a[0] += bflo(u4.x); a[1] += bfhi(u4.x);
        a[2] += bflo(u4.y); a[3] += bfhi(u4.y);
        a[4] += bflo(u4.z); a[5] += bfhi(u4.z);
        a[6] += bflo(u4.w); a[7] += bfhi(u4.w);
      }
    }
#pragma unroll
    for (int i = 0; i < 8; i++) a[i] += __shfl_xor(a[i], 4, 64);
    if (h == 0) {
      uint4 w;
      w.x = packbf(a[0], a[1]); w.y = packbf(a[2], a[3]);
      w.z = packbf(a[4], a[5]); w.w = packbf(a[6], a[7]);
      *(uint4*)&zsA[node * 40 + q4 * 8] = w;
    }
  }
  __syncthreads();
  gemm_tiles<1, 2, true>(zsA, 40, zsB, wf + 0 * 64, b1, wid >> 1,
                         (wid & 1) * 2, lane);
  __syncthreads();
  gemm_tiles<2, 2, false>(zsB, 72, zsA, wf + 4 * 64, b2, wid >> 1,
                          (wid & 1) * 2, lane);
  __syncthreads();

  for (int i = tid; i < 64 * 8; i += 512) {
    const int row = i >> 3, q = i & 7;
    if (n0 + row < n)
      ((short8*)h0bf)[(size_t)(n0 + row) * 8 + q] =
          *(const short8*)&zsA[row * 72 + q * 8];
  }
}

// ---------------------------------------------------------------------------
// fused1: gather(h0bf, D=64) -> GEMM(w1_1)+relu -> GEMM(w2_1) -> GEMM(cw1)
// +relu -> GEMM(cw2,N=16) -> out f32. 512 thr, 32 nodes/block, 16 thr/node
// (q4 = sub&7, h = sub>>3), shfl lane^8.
// ---------------------------------------------------------------------------
__global__ __launch_bounds__(512) void fused1_kernel(
    const uint4* __restrict__ hbf, const int* __restrict__ off,
    const int* __restrict__ csr, const short8* __restrict__ wf,
    const float* __restrict__ b1, const float* __restrict__ b2,
    const float* __restrict__ cb1, const float* __restrict__ cb2,
    float* __restrict__ out, int n) {
  __shared__ unsigned short zsA[32 * 72];
  __shared__ unsigned short zsB[32 * 72];
  const int tid = threadIdx.x;
  const int lane = tid & 63;
  const int wid = tid >> 6;
  const int n0 = blockIdx.x * 32;
  const int l15 = lane & 15, lh = lane >> 4;

  {
    const int node = tid >> 4;
    const int sub = tid & 15;
    const int q4 = sub & 7;
    const int h = sub >> 3;
    const int g = n0 + node;
    float a[8];
#pragma unroll
    for (int i = 0; i < 8; i++) a[i] = 0.f;
    if (g < n) {
      if (h == 0) {
        const uint4 u = hbf[(size_t)g * 8 + q4];
        a[0] = bflo(u.x); a[1] = bfhi(u.x); a[2] = bflo(u.y); a[3] = bfhi(u.y);
        a[4] = bflo(u.z); a[5] = bfhi(u.z); a[6] = bflo(u.w); a[7] = bfhi(u.w);
      }
      const int e0 = off[g], e1 = off[g + 1];
      int e = e0 + h;
      for (; e + 6 < e1; e += 8) {
        const int s0 = csr[e], s1 = csr[e + 2], s2 = csr[e + 4],
                  s3 = csr[e + 6];
        const uint4 u0 = hbf[(size_t)s0 * 8 + q4];
        const uint4 u1 = hbf[(size_t)s1 * 8 + q4];
        const uint4 u2 = hbf[(size_t)s2 * 8 + q4];
        const uint4 u3 = hbf[(size_t)s3 * 8 + q4];
        a[0] += bflo(u0.x) + bflo(u1.x) + bflo(u2.x) + bflo(u3.x);
        a[1] += bfhi(u0.x) + bfhi(u1.x) + bfhi(u2.x) + bfhi(u3.x);
        a[2] += bflo(u0.y) + bflo(u1.y) + bflo(u2.y) + bflo(u3.y);
        a[3] += bfhi(u0.y) + bfhi(u1.y) + bfhi(u2.y) + bfhi(u3.y);
        a[4] += bflo(u0.z) + bflo(u1.z) + bflo(u2.z) + bflo(u3.z);
        a[5] += bfhi(u0.z) + bfhi(u1.z) + bfhi(u2.z) + bfhi(u3.z);
        a[6] += bflo(u0.w) + bflo(u1.w) + bflo(u2.w) + bflo(u3.w);
        a[7] += bfhi(u0.w) + bfhi(u1.w) + bfhi(u2.w) + bfhi(u3.w);
      }
      for (; e < e1; e += 2) {
        const uint4 u4 = hbf[(size_t)csr[e] * 8 + q4];
        a[0] += bflo(u4.x); a[1] += bfhi(u4.x);
        a[2] += bflo(u4.y); a[3] += bfhi(u4.y);
        a[4] += bflo(u4.z); a[5] += bfhi(u4.z);
        a[6] += bflo(u4.w); a[7] += bfhi(u4.w);
      }
    }
#pragma unroll
    for (int i = 0; i < 8; i++) a[i] += __shfl_xor(a[i], 8, 64);
    if (h == 0) {
      uint4 w;
      w.x = packbf(a[0], a[1]); w.y = packbf(a[2], a[3]);
      w.z = packbf(a[4], a[5]); w.w = packbf(a[6], a[7]);
      *(uint4*)&zsA[node * 72 + q4 * 8] = w;
    }
  }
  __syncthreads();
  gemm_tiles<2, 1, true>(zsA, 72, zsB, wf + 12 * 64, b1, wid & 1, wid >> 1,
                         lane);  // z1
  __syncthreads();
  gemm_tiles<2, 1, false>(zsB, 72, zsA, wf + 20 * 64, b2, wid & 1, wid >> 1,
                          lane);  // h1
  __syncthreads();
  gemm_tiles<2, 1, true>(zsA, 72, zsB, wf + 28 * 64, cb1, wid & 1, wid >> 1,
                         lane);  // z2
  __syncthreads();

  // GEMM4: K=64, N=16 (cw2) -> f32 out (2 M-tiles on waves 0-1)
  f32x4 acc = (f32x4){0.f, 0.f, 0.f, 0.f};
  if (wid < 2) {
    const short8 bf0 = wf[36 * 64 + lane];
    const short8 bf1 = wf[37 * 64 + lane];
#pragma unroll
    for (int kb = 0; kb < 2; kb++) {
      const short8 a =
          *(const short8*)&zsB[(wid * 16 + l15) * 72 + kb * 32 + lh * 8];
      acc = __builtin_amdgcn_mfma_f32_16x16x32_bf16(a, kb ? bf1 : bf0, acc, 0,
                                                    0, 0);
    }
  }
  __syncthreads();
  if (wid < 2) {
    float* zf = (float*)zsA;  // [32][20] f32
    const float bb = cb2[l15];
#pragma unroll
    for (int r = 0; r < 4; r++)
      zf[(wid * 16 + lh * 4 + r) * 20 + l15] = acc[r] + bb;
  }
  __syncthreads();
  {
    float* zf = (float*)zsA;
    for (int i = tid; i < 128; i += 512) {
      const int row = i >> 2, q = i & 3;
      if (n0 + row < n)
        ((float4*)out)[(size_t)(n0 + row) * 4 + q] =
            *(const float4*)&zf[row * 20 + q * 4];
    }
  }
}

extern "C" void kernel_launch(void* const* d_in, const int* in_sizes, int n_in,
                              void* d_out, int out_size, void* d_ws,
                              size_t ws_size, hipStream_t stream) {
  const float* x = (const float*)d_in[0];
  const int* ei = (const int*)d_in[1];
  const float* w1_0 = (const float*)d_in[2];
  const float* b1_0 = (const float*)d_in[3];
  const float* w2_0 = (const float*)d_in[4];
  const float* b2_0 = (const float*)d_in[5];
  const float* w1_1 = (const float*)d_in[6];
  const float* b1_1 = (const float*)d_in[7];
  const float* w2_1 = (const float*)d_in[8];
  const float* b2_1 = (const float*)d_in[9];
  const float* cw1 = (const float*)d_in[10];
  const float* cb1 = (const float*)d_in[11];
  const float* cw2 = (const float*)d_in[12];
  const float* cb2 = (const float*)d_in[13];

  const int n = in_sizes[0] / 32;  // nodes (< 2^17 for packing)
  const int ne = in_sizes[1] / 2;  // edges
  const int* src = ei;
  const int* dst = ei + ne;
  const int nb = (n + NPB - 1) / NPB;

  // Workspace layout (16B-aligned uint4 region first, then ints)
  uint4* h0bf = (uint4*)d_ws;                  // n*8  (bf16 [n][64])
  uint4* xbf = h0bf + (size_t)n * 8;           // n*4  (bf16 [n][32])
  uint4* wfrag = xbf + (size_t)n * 4;          // 38*64
  int* sorted = (int*)(wfrag + 38 * 64);       // ne
  int* csr = sorted + ne;                      // ne
  int* off = csr + ne;                         // n+1
  int* hist_part = off + n + 1;                // nb*NH
  int* boff = hist_part + (size_t)nb * NH;     // nb+1
  int* bcur = boff + nb + 1;                   // nb

  // prep: partial hists (race-free) + x->bf16 + weight repack, one launch
  {
    const int n4 = n * 8;
    prep_kernel<<<NH + 1 + (n4 + 255) / 256, 256, 0, stream>>>(
        (const float4*)x, (uint2*)xbf, n4, dst, ne, nb, hist_part, w1_0, w2_0,
        w1_1, w2_1, cw1, cw2, wfrag);
  }

  // --- CSR build ---
  bucket_scan_kernel<<<1, 512, 0, stream>>>(hist_part, boff, bcur, nb, ne);
  partition_kernel<<<(ne + CHUNK - 1) / CHUNK, 256, 0, stream>>>(
      src, dst, bcur, sorted, ne, nb);
  fill_bucket_kernel<<<nb, 256, 0, stream>>>(sorted, boff, off, csr, n, ne);

  const short8* wf = (const short8*)wfrag;

  fused0_kernel<<<(n + 63) / 64, 512, 0, stream>>>(xbf, off, csr, wf, b1_0,
                                                   b2_0, h0bf, n);
  fused1_kernel<<<(n + 31) / 32, 512, 0, stream>>>(h0bf, off, csr, wf, b1_1,
                                                   b2_1, cb1, cb2,
                                                   (float*)d_out, n);
}